// Round 9
// baseline (194.240 us; speedup 1.0000x reference)
//
#include <hip/hip_runtime.h>
#include <hip/hip_fp16.h>

#define NN 100000
#define NB 391        // ceil(NN/256) buckets of 256 dst nodes
#define NG 256        // edge-pass blocks
#define CHUNK_CAP 8192
#define SWCAP 12288   // per-bucket edge capacity (LDS + csr region)
#define REGION 12288

using f16x8 = __attribute__((ext_vector_type(8))) _Float16;
using f32x4 = __attribute__((ext_vector_type(4))) float;

// ---------------- pass 1: per-block local bucket sort of edge chunk ----------------
// staging[lo..lo+n) = this block's edges grouped by bucket; meta[bk][g] = local excl offset
__global__ __launch_bounds__(256) void bsort_kernel(const int* __restrict__ src,
                                                    const int* __restrict__ dst,
                                                    int* __restrict__ staging,
                                                    int* __restrict__ meta, int E) {
    __shared__ int sdst[CHUNK_CAP];
    __shared__ int sh[512];
    __shared__ int cur[NB];
    const int g = blockIdx.x, t = threadIdx.x;
    const int chunk = (E + NG - 1) / NG;
    const int lo = g * chunk;
    const int n = min(E - lo, chunk);          // may be <=0 for overshoot blocks
    for (int i = t; i < n; i += 256) sdst[i] = dst[lo + i];
    sh[t] = 0; sh[t + 256] = 0;
    __syncthreads();
    for (int i = t; i < n; i += 256) atomicAdd(&sh[sdst[i] >> 8], 1);
    __syncthreads();
    // Hillis-Steele inclusive scan over 512
    for (int off = 1; off < 512; off <<= 1) {
        int a0 = (t >= off) ? sh[t - off] : 0;
        int a1 = sh[t + 256 - off];
        __syncthreads();
        sh[t] += a0; sh[t + 256] += a1;
        __syncthreads();
    }
    // exclusive offsets -> meta + cur
    {
        int bk = t;
        int excl = (bk == 0) ? 0 : sh[bk - 1];
        if (bk < NB) { meta[bk * NG + g] = excl; cur[bk] = excl; }
        bk = t + 256;
        if (bk < NB) { int e2 = sh[bk - 1]; meta[bk * NG + g] = e2; cur[bk] = e2; }
    }
    __syncthreads();
    for (int i = t; i < n; i += 256) {
        int d = sdst[i];
        int pos = atomicAdd(&cur[d >> 8], 1);
        staging[lo + pos] = src[lo + i] | ((d & 255) << 17);
    }
}

// ---------------- pass 2: per-bucket CSR finalize + row_beg/row_end + dis + x->fp16 ----------------
__global__ __launch_bounds__(256) void bfinal_kernel(const int* __restrict__ staging,
                                                     const int* __restrict__ meta,
                                                     int* __restrict__ csr,
                                                     int* __restrict__ row_beg,
                                                     int* __restrict__ row_end,
                                                     float* __restrict__ dis,
                                                     const float* __restrict__ x,
                                                     __half* __restrict__ xh,
                                                     int N, int E) {
    __shared__ int swords[SWCAP];
    __shared__ int segoff[NG], seglen[NG], ldst_[NG];
    __shared__ int sh[256], cur[256];
    __shared__ float sdis[256];
    const int b = blockIdx.x, t = threadIdx.x;
    const int chunk = (E + NG - 1) / NG;
    // segment metadata for this bucket across all 256 source blocks
    int off0 = meta[b * NG + t];
    int nxt;
    if (b < NB - 1) nxt = meta[(b + 1) * NG + t];
    else { int ng2 = min(E - t * chunk, chunk); nxt = (ng2 > 0) ? ng2 : 0; }
    int len = nxt - off0; if (len < 0) len = 0;
    segoff[t] = off0; seglen[t] = len;
    sh[t] = len;
    __syncthreads();
    for (int off = 1; off < 256; off <<= 1) {
        int v = (t >= off) ? sh[t - off] : 0;
        __syncthreads();
        sh[t] += v;
        __syncthreads();
    }
    int T = sh[255];
    ldst_[t] = sh[t] - len;
    __syncthreads();
    // gather segments into LDS (4 waves, 64 segments each)
    const int w = t >> 6, lane = t & 63;
    for (int g = w; g < NG; g += 4) {
        int sl = seglen[g], so = segoff[g], dl = ldst_[g];
        for (int i = lane; i < sl; i += 64) {
            int idx = dl + i;
            if (idx < SWCAP) swords[idx] = staging[g * chunk + so + i];
        }
    }
    if (T > SWCAP) T = SWCAP;
    sh[t] = 0;          // reuse as node hist
    __syncthreads();
    for (int i = t; i < T; i += 256) atomicAdd(&sh[swords[i] >> 17], 1);
    __syncthreads();
    int v = sh[t];
    __syncthreads();
    sh[t] = v;
    __syncthreads();
    for (int off = 1; off < 256; off <<= 1) {
        int u = (t >= off) ? sh[t - off] : 0;
        __syncthreads();
        sh[t] += u;
        __syncthreads();
    }
    int excl = sh[t] - v;
    const int base = b * REGION;
    cur[t] = base + excl;
    float dv = rsqrtf((float)v + 1.0f);
    sdis[t] = dv;
    int node = b * 256 + t;
    if (node < N) {
        row_beg[node] = base + excl;
        row_end[node] = base + excl + v;
        dis[node]     = dv;
    }
    __syncthreads();
    for (int i = t; i < T; i += 256) {
        int word = swords[i];
        int pos = atomicAdd(&cur[word >> 17], 1);
        csr[pos] = word & 0x1FFFF;
    }
    // fused: xh[node] = dis[node]*x[node] (fp16)
    const int node0 = b * 256;
    const int nmax = min(256, N - node0);
    for (int i = t; i < nmax * 16; i += 256) {
        int nl = i >> 4, c4 = i & 15;
        float4 vx = ((const float4*)x)[(size_t)(node0 + nl) * 16 + c4];
        float wq = sdis[nl];
        __half2* o = (__half2*)&xh[(size_t)(node0 + nl) * 64 + c4 * 4];
        o[0] = __floats2half2_rn(vx.x * wq, vx.y * wq);
        o[1] = __floats2half2_rn(vx.z * wq, vx.w * wq);
    }
}

// ---------------- both weight transposes in one launch ----------------
__global__ void cvtW_kernel(const float* __restrict__ W1, const float* __restrict__ W2,
                            __half* __restrict__ W1t, __half* __restrict__ W2t) {
    int i = blockIdx.x * 256 + threadIdx.x;
    if (i < 64 * 128) {
        int k = i / 128, c = i % 128;
        W1t[c * 64 + k] = __float2half(W1[i]);
        // second matrix same flat size
        int k2 = i / 64, c2 = i % 64;
        W2t[c2 * 128 + k2] = __float2half(W2[i]);
    }
}

// ---------------- MFMA GEMM: C[N,F](fp16) = A[N,K](fp16) @ Wt[F,K]^T, epilogue ----------------
// EPI 0: relu(acc + bias[col]); EPI 1: acc * dis[row]
template<int K, int F, int EPI>
__global__ __launch_bounds__(256) void gemm_mfma_kernel(const __half* __restrict__ A,
                                                        const __half* __restrict__ Wt,
                                                        const float* __restrict__ bias,
                                                        const float* __restrict__ dis,
                                                        __half* __restrict__ C, int N) {
    constexpr int BM = 32;
    constexpr int NT = F / 32;
    const int wid  = threadIdx.x >> 6;
    const int lane = threadIdx.x & 63;
    const int wr = wid >> 1;
    const int wc = wid & 1;
    const int row0 = blockIdx.x * BM + wr * 16;
    const int col0 = wc * (F / 2);
    const int lrow = lane & 15;
    const int kgrp = lane >> 4;

    f32x4 acc[NT];
    #pragma unroll
    for (int nt = 0; nt < NT; ++nt) acc[nt] = (f32x4){0.f, 0.f, 0.f, 0.f};

    #pragma unroll
    for (int ks = 0; ks < K / 32; ++ks) {
        const int kbase = ks * 32 + kgrp * 8;
        f16x8 a = *reinterpret_cast<const f16x8*>(&A[(size_t)(row0 + lrow) * K + kbase]);
        #pragma unroll
        for (int nt = 0; nt < NT; ++nt) {
            f16x8 b = *reinterpret_cast<const f16x8*>(&Wt[(size_t)(col0 + nt * 16 + lrow) * K + kbase]);
            acc[nt] = __builtin_amdgcn_mfma_f32_16x16x32_f16(a, b, acc[nt], 0, 0, 0);
        }
    }
    #pragma unroll
    for (int nt = 0; nt < NT; ++nt) {
        const int col = col0 + nt * 16 + lrow;
        float bb = (EPI == 0) ? bias[col] : 0.0f;
        #pragma unroll
        for (int r = 0; r < 4; ++r) {
            const int row = row0 + kgrp * 4 + r;
            float v = acc[nt][r];
            if (EPI == 0) v = fmaxf(v + bb, 0.0f);
            else          v = v * dis[row];
            C[(size_t)row * F + col] = __float2half(v);
        }
    }
}

// ---------------- gather: 1 wave/node, 16 edges/iter, fma_mix accumulate ----------------
template<bool BIAS, typename OutT>
__global__ __launch_bounds__(256) void gather64v3_kernel(const __half* __restrict__ tab,
                                                         const float* __restrict__ dis,
                                                         const float* __restrict__ b,
                                                         const int* __restrict__ row_beg,
                                                         const int* __restrict__ row_end,
                                                         const int* __restrict__ csr_src,
                                                         OutT* __restrict__ out, int N,
                                                         float one) {
    const int node = blockIdx.x * 4 + (threadIdx.x >> 6);
    const int lane = threadIdx.x & 63;
    const int g   = lane >> 3;
    const int sub = lane & 7;
    if (node >= N) return;
    const int beg = row_beg[node], end = row_end[node];

    float acc[8];
    {   // self-loop row counted once via group 0
        f16x8 sv = *reinterpret_cast<const f16x8*>(&tab[(size_t)node * 64 + sub * 8]);
        #pragma unroll
        for (int q = 0; q < 8; ++q) acc[q] = (g == 0) ? (float)sv[q] : 0.0f;
    }

    int j = beg;
    for (; j + 16 <= end; j += 16) {
        int sA = csr_src[j + g];
        int sB = csr_src[j + 8 + g];
        f16x8 vA = *reinterpret_cast<const f16x8*>(&tab[(size_t)sA * 64 + sub * 8]);
        f16x8 vB = *reinterpret_cast<const f16x8*>(&tab[(size_t)sB * 64 + sub * 8]);
        #pragma unroll
        for (int q = 0; q < 8; ++q) acc[q] = fmaf((float)vA[q], one, acc[q]);
        #pragma unroll
        for (int q = 0; q < 8; ++q) acc[q] = fmaf((float)vB[q], one, acc[q]);
    }
    if (j + 8 <= end) {
        int s = csr_src[j + g];
        f16x8 v = *reinterpret_cast<const f16x8*>(&tab[(size_t)s * 64 + sub * 8]);
        #pragma unroll
        for (int q = 0; q < 8; ++q) acc[q] = fmaf((float)v[q], one, acc[q]);
        j += 8;
    }
    if (j + g < end) {
        int s = csr_src[j + g];
        f16x8 v = *reinterpret_cast<const f16x8*>(&tab[(size_t)s * 64 + sub * 8]);
        #pragma unroll
        for (int q = 0; q < 8; ++q) acc[q] = fmaf((float)v[q], one, acc[q]);
    }

    #pragma unroll
    for (int q = 0; q < 8; ++q) {
        acc[q] += __shfl_xor(acc[q], 8);
        acc[q] += __shfl_xor(acc[q], 16);
        acc[q] += __shfl_xor(acc[q], 32);
    }

    if (g == 0) {
        const float dd = dis[node];
        if constexpr (sizeof(OutT) == 2) {
            f16x8 o;
            #pragma unroll
            for (int q = 0; q < 8; ++q) {
                float v = acc[q] * dd;
                if (BIAS) v += b[sub * 8 + q];
                o[q] = (_Float16)v;
            }
            *reinterpret_cast<f16x8*>(&out[(size_t)node * 64 + sub * 8]) = o;
        } else {
            float vv[8];
            #pragma unroll
            for (int q = 0; q < 8; ++q) {
                float v = acc[q] * dd;
                if (BIAS) v += b[sub * 8 + q];
                vv[q] = v;
            }
            float* op = (float*)&out[(size_t)node * 64 + sub * 8];
            *reinterpret_cast<float4*>(op)     = make_float4(vv[0], vv[1], vv[2], vv[3]);
            *reinterpret_cast<float4*>(op + 4) = make_float4(vv[4], vv[5], vv[6], vv[7]);
        }
    }
}

extern "C" void kernel_launch(void* const* d_in, const int* in_sizes, int n_in,
                              void* d_out, int out_size, void* d_ws, size_t ws_size,
                              hipStream_t stream) {
    const float* x  = (const float*)d_in[0];
    const int*   ei = (const int*)d_in[1];
    const float* W1 = (const float*)d_in[2];
    const float* b1 = (const float*)d_in[3];
    const float* W2 = (const float*)d_in[4];
    const float* b2 = (const float*)d_in[5];
    float* out = (float*)d_out;

    const int N = NN;
    const int E = in_sizes[1] / 2;
    const int* src = ei;
    const int* dst = ei + E;

    // workspace layout (4-byte words)
    int* meta     = (int*)d_ws;                     // NB*NG
    int* staging  = meta + NB * NG;                 // E
    int* row_beg  = staging + E;                    // N
    int* row_end  = row_beg + N;                    // N
    float* dis    = (float*)(row_end + N);          // N
    int* csr      = (int*)(dis + N);                // NB*REGION
    float* base   = (float*)(csr + (size_t)NB * REGION);
    __half* xh    = (__half*)base;                      // N*64 halves
    __half* aggh  = (__half*)(base + (size_t)N * 32);   // N*64
    __half* zh    = (__half*)(base + (size_t)N * 64);   // N*64
    __half* h1h   = (__half*)(base + (size_t)N * 96);   // N*128
    __half* W1t   = (__half*)(base + (size_t)N * 160);  // 8192 halves
    __half* W2t   = W1t + 128 * 64;                     // 8192 halves

    // ---- CSR build: 2 kernels, no global scan/atomics ----
    bsort_kernel<<<NG, 256, 0, stream>>>(src, dst, staging, meta, E);
    bfinal_kernel<<<NB, 256, 0, stream>>>(staging, meta, csr, row_beg, row_end, dis, x, xh, N, E);

    // ---- weights ----
    cvtW_kernel<<<(64 * 128 + 255) / 256, 256, 0, stream>>>(W1, W2, W1t, W2t);

    // ---- layer 1: aggh = A_hat-gather(xh), h1h = relu(aggh@W1+b1) ----
    gather64v3_kernel<false, __half><<<(N + 3) / 4, 256, 0, stream>>>(xh, dis, nullptr, row_beg, row_end, csr, aggh, N, 1.0f);
    gemm_mfma_kernel<64, 128, 0><<<N / 32, 256, 0, stream>>>(aggh, W1t, b1, nullptr, h1h, N);

    // ---- layer 2: zh = (h1h@W2)*dis, out = A_hat-gather(zh) + b2 ----
    gemm_mfma_kernel<128, 64, 1><<<N / 32, 256, 0, stream>>>(h1h, W2t, nullptr, dis, zh, N);
    gather64v3_kernel<true, float><<<(N + 3) / 4, 256, 0, stream>>>(zh, dis, b2, row_beg, row_end, csr, out, N, 1.0f);
}